// Round 18
// baseline (95.807 us; speedup 1.0000x reference)
//
#include <hip/hip_runtime.h>
#include <math.h>

#define B_ 4
#define N_ 4096
#define BN_ (B_*N_)
#define NT 64                 /* 64 tiles of 64 rows */
#define NCH 2                 /* k=0: c in [0,17), k=1: c in [17,33) */

typedef __bf16 v8bf __attribute__((ext_vector_type(8)));
typedef unsigned short u16x8 __attribute__((ext_vector_type(8)));
typedef float v4f __attribute__((ext_vector_type(4)));
typedef float v2f __attribute__((ext_vector_type(2)));

#define LOG2E 1.44269504088896340736f
#define CPROX (-50.0f*LOG2E)            /* -1/(2*sigma^2) * log2(e) */
#define INVSQRT3 0.57735026918962576f
/* smoothstep sigmoid approx: sigmoid(5(s-tau)) ~ S((s-tau)/1.4 + 0.5) */
#define GS (1.0f/1.4f)
#define GC_FLOW  (0.5f - 0.8f*GS)
#define GC_COLOR (0.5f - 0.7f*GS)
#define GC_PROX  (0.5f - 0.5f*GS)
/* prox fast path: d2p > 0.09 (d > 0.3) -> spr = exp(-50d) <= 3e-7 ~ 0 */
#define D2P_MIN 0.09f

__device__ __forceinline__ float fexp2(float x){ return __builtin_amdgcn_exp2f(x); }
__device__ __forceinline__ float fsqrt(float x){ return __builtin_amdgcn_sqrtf(x); }

// packed smoothstep gate on a float2 of (r, r+1) pairs
#define PKGATE(s2_, gcv_, SPA, SMA, CPA, CPB)                          \
  { v2f t_ = s2_*GSv + gcv_;                                           \
    t_ = __builtin_elementwise_max(t_, zerov);                         \
    t_ = __builtin_elementwise_min(t_, onev);                          \
    v2f t2_ = t_*t_;                                                   \
    v2f u_  = t_*m2v + c3v;                                            \
    v2f a_  = (t2_*u_)*fsl;                                            \
    v2f e1_ = {fexp2(a_.x), fexp2(a_.y)};                              \
    v2f e2_ = E2*e1_;                                                  \
    SPA += e1_; SMA += e2_; CPA += e1_; CPB += e2_; }

// ---------------- prep: normalize features -> bf16, per-point scalars ----------------
extern "C" __global__ __launch_bounds__(256) void prep_k(
    const float* __restrict__ flow, const float* __restrict__ color,
    const float* __restrict__ coord, const float* __restrict__ feat,
    unsigned short* __restrict__ fn, float* __restrict__ scal)
{
  const int wave = blockIdx.x*4 + (threadIdx.x>>6);
  const int lane = threadIdx.x & 63;
  float v = feat[(size_t)wave*64 + lane];
  float ss = v*v;
  #pragma unroll
  for (int d=32; d; d>>=1) ss += __shfl_xor(ss, d);
  float sc = 1.0f/(sqrtf(ss)+1e-7f);     // matches ref: f/(||f||+1e-7)
  float x = v*sc;
  unsigned u = __builtin_bit_cast(unsigned, x);
  unsigned r = (u + 0x7fffu + ((u>>16)&1u)) >> 16;   // RN-even f32->bf16
  fn[(size_t)wave*64+lane] = (unsigned short)r;
  if (lane==0) {
    float fx=flow[wave*3+0], fy=flow[wave*3+1], fz=flow[wave*3+2];
    float rn = 1.0f/sqrtf(fx*fx+fy*fy+fz*fz + 1e-8f);
    const float k = 1.0f/255.0f;
    float cx=color[wave*3+0]*k, cy=color[wave*3+1]*k, cz=color[wave*3+2]*k;
    float px=coord[wave*3+0], py=coord[wave*3+1], pz=coord[wave*3+2];
    float* o = scal + (size_t)wave*12;
    o[0]=fx*rn; o[1]=fy*rn; o[2]=fz*rn;
    o[3]=cx; o[4]=cy; o[5]=cz;
    o[6]=cx*cx+cy*cy+cz*cz;
    o[7]=px; o[8]=py; o[9]=pz;
    o[10]=px*px+py*py+pz*pz;
    o[11]=0.f;
  }
}

// ---------- main: symmetric ring tiles, double-buffered, packed-f32 epilogue ----------
// block (b, ti, k): j-tiles tj=(ti+c)&63; k=0: c=0..16 (17 tiles), k=1: c=17..32 (16).
// c=0 (diag) and c=32 (antipode, computed from both ends) are rows-only.
// Column flush only for c in [1,31]: every unordered tile-pair counted once.
// (256,2): compiler VGPR budget = 256/min_waves (R5/R11/R16); live set ~112 needs 128.
// Prox fast path (R18): wave-uniform skip of sqrt+exp2 when all d2p > 0.09.
extern "C" __global__ __launch_bounds__(256,2) void main_k(
    const unsigned short* __restrict__ fn, const float* __restrict__ scal,
    float* __restrict__ part_row, float* __restrict__ part2)
{
  __shared__ unsigned short fnj[2][64*64];   // 2 x 8 KB, XOR-swizzled rows (128B each)
  __shared__ float scj[2][64*12];            // 2 x 3 KB
  __shared__ float colacc[2][4][64][6];      // 2 x 6 KB per-wave column partials

  const int ti = blockIdx.x & 63;
  const int k  = blockIdx.x >> 6;            // 0..1
  const int b  = blockIdx.y;
  const int c0 = k*17;
  const int npt = 17 - k;                    // 17 or 16 tiles

  const int tid  = threadIdx.x;
  const int w    = tid >> 6;
  const int lane = tid & 63;
  const int g    = lane >> 4;
  const int col  = lane & 15;
  const int irow0 = ti*64 + w*16;

  const unsigned short* fnb = fn + (size_t)b*N_*64;
  const float* scb = scal + (size_t)b*N_*12;

  // staging geometry (each thread: 2 fn-rows-of-16B + 1 scj-16B if tid<192)
  const int srow = tid>>3, sseg = tid&7;
  const int ssw  = (srow&7)<<4;              // (srow+32)&7 == srow&7
  const int scrow = tid/3, scseg = tid-3*(tid/3);

  // A fragments: row = lane&15, kk = (lane>>4)*8 + e (two K=32 halves), held in regs
  const int arow = irow0 + col;
  v8bf a0 = __builtin_bit_cast(v8bf, *(const u16x8*)(fnb + (size_t)arow*64 + g*8));
  v8bf a1 = __builtin_bit_cast(v8bf, *(const u16x8*)(fnb + (size_t)arow*64 + 32 + g*8));

  // i-side scalars packed as float2 over row-pairs (r, r+1), rp in {0,1}
  v2f fhi[2][3], ci2[2][3], pi2[2][3];
  #pragma unroll
  for (int rp=0;rp<2;++rp) {
    const float* sA = scb + (size_t)(irow0 + g*4 + 2*rp)*12;
    const float* sB = sA + 12;
    v4f a0s = *(const v4f*)(sA), a1s = *(const v4f*)(sA+4), a2s = *(const v4f*)(sA+8);
    v4f b0s = *(const v4f*)(sB), b1s = *(const v4f*)(sB+4), b2s = *(const v4f*)(sB+8);
    fhi[rp][0] = (v2f){a0s.x, b0s.x}; fhi[rp][1] = (v2f){a0s.y, b0s.y}; fhi[rp][2] = (v2f){a0s.z, b0s.z};
    ci2[rp][0] = (v2f){a0s.w, b0s.w}; ci2[rp][1] = (v2f){a1s.x, b1s.x}; ci2[rp][2] = (v2f){a1s.y, b1s.y};
    pi2[rp][0] = (v2f){a1s.w, b1s.w}; pi2[rp][1] = (v2f){a2s.x, b2s.x}; pi2[rp][2] = (v2f){a2s.y, b2s.y};
  }

  const v2f zerov = {0.f,0.f}, onev = {1.f,1.f};
  const v2f GSv = {GS,GS}, m2v = {-2.f,-2.f}, c3v = {3.f,3.f};
  const v2f gcF = {GC_FLOW,GC_FLOW}, gcC = {GC_COLOR,GC_COLOR}, gcP = {GC_PROX,GC_PROX};
  const v2f l2e = {LOG2E,LOG2E}, cprx = {CPROX,CPROX}, nis3 = {-INVSQRT3,-INVSQRT3};

  // row accumulators, packed over row-pairs
  v2f spa2[3][2], sma2[3][2];
  #pragma unroll
  for (int l=0;l<3;++l)
    #pragma unroll
    for (int rp=0;rp<2;++rp){ spa2[l][rp]=zerov; sma2[l][rp]=zerov; }

  // prologue: stage first tile into buffer 0
  {
    const int tj = (ti + c0) & 63;
    const unsigned short* fng = fnb + (size_t)tj*4096;
    const float* scg = scb + (size_t)tj*768;
    float4 f0 = *(const float4*)(fng + (size_t)srow*64 + sseg*8);
    float4 f1 = *(const float4*)(fng + (size_t)(srow+32)*64 + sseg*8);
    *(float4*)((char*)fnj[0] + srow*128 + ((sseg*16)^ssw)) = f0;
    *(float4*)((char*)fnj[0] + (srow+32)*128 + ((sseg*16)^ssw)) = f1;
    if (tid < 192)
      *(float4*)(scj[0] + scrow*12 + scseg*4) = *(const float4*)(scg + (size_t)scrow*12 + scseg*4);
  }
  __syncthreads();

  int cprev=-1, tjprev=0;
  for (int t2=0; t2<npt; ++t2) {
    const int p  = t2&1;
    const int c  = c0 + t2;
    const int tj = (ti + c) & 63;
    const bool docol = (c>=1 && c<=31);
    const bool more  = (t2<npt-1);

    // (A) stage LOADS for next tile (latency hides under compute — T14)
    float4 f0, f1, sv;
    if (more) {
      const int tjn = (ti + c + 1) & 63;
      const unsigned short* fng = fnb + (size_t)tjn*4096;
      const float* scg = scb + (size_t)tjn*768;
      f0 = *(const float4*)(fng + (size_t)srow*64 + sseg*8);
      f1 = *(const float4*)(fng + (size_t)(srow+32)*64 + sseg*8);
      if (tid < 192) sv = *(const float4*)(scg + (size_t)scrow*12 + scseg*4);
    }

    // (B) flush previous tile's columns (post-barrier, overlaps this compute)
    if (t2>0 && cprev>=1 && cprev<=31) {
      const int pp = p^1;
      for (int s=tid; s<384; s+=256) {
        int jl=s/6, kk=s-6*jl;
        float v = colacc[pp][0][jl][kk]+colacc[pp][1][jl][kk]
                + colacc[pp][2][jl][kk]+colacc[pp][3][jl][kk];
        part2[(((size_t)b*31 + (cprev-1))*N_ + tjprev*64 + jl)*6 + kk] = v;
      }
    }

    // (C) compute current tile from buffers [p]
    #pragma unroll
    for (int sub=0; sub<4; ++sub) {
      const int jloc = sub*16 + col;
      const int sw = (jloc&7)<<4;
      const char* rowp = (const char*)fnj[p] + jloc*128;
      v8bf b0 = __builtin_bit_cast(v8bf, *(const u16x8*)(rowp + ((g*16) ^ sw)));
      v8bf b1 = __builtin_bit_cast(v8bf, *(const u16x8*)(rowp + ((64 + g*16) ^ sw)));
      v4f j0 = *(const v4f*)(scj[p] + jloc*12);
      v4f j1 = *(const v4f*)(scj[p] + jloc*12 + 4);
      v4f j2 = *(const v4f*)(scj[p] + jloc*12 + 8);

      v4f acc = {0.f,0.f,0.f,0.f};
      acc = __builtin_amdgcn_mfma_f32_16x16x32_bf16(a0, b0, acc, 0,0,0);
      acc = __builtin_amdgcn_mfma_f32_16x16x32_bf16(a1, b1, acc, 0,0,0);

      // j-side splats
      const v2f jf0={j0.x,j0.x}, jf1={j0.y,j0.y}, jf2={j0.z,j0.z};
      const v2f jc0={j0.w,j0.w}, jc1={j1.x,j1.x}, jc2={j1.y,j1.y};
      const v2f jp0={j1.w,j1.w}, jp1={j2.x,j2.x}, jp2={j2.y,j2.y};

      v2f cp0=zerov, cp1=zerov, cp2=zerov, cp3=zerov, cp4=zerov, cp5=zerov;

      #pragma unroll
      for (int rp=0;rp<2;++rp) {
        const v2f fs = {acc[2*rp], acc[2*rp+1]};    // feature cosines, 2 rows
        const v2f sf = fhi[rp][0]*jf0 + fhi[rp][1]*jf1 + fhi[rp][2]*jf2;   // flow cos
        v2f dc0 = ci2[rp][0]-jc0, dc1 = ci2[rp][1]-jc1, dc2 = ci2[rp][2]-jc2;
        v2f d2c = dc0*dc0 + dc1*dc1 + dc2*dc2;
        v2f sq_c = {fsqrt(d2c.x), fsqrt(d2c.y)};
        const v2f scl = sq_c*nis3 + onev;                                  // color sim
        v2f dp0 = pi2[rp][0]-jp0, dp1 = pi2[rp][1]-jp1, dp2 = pi2[rp][2]-jp2;
        v2f d2p = dp0*dp0 + dp1*dp1 + dp2*dp2;
        // prox sim with wave-uniform fast path: spr ~ 0 unless some lane is
        // near-coincident (d2p < 0.09 -> spr >= 3e-7). Skips sqrt+exp2 (2 of
        // 7 trans ops/pair) for ~100% of waves on random data; exact path
        // taken by the whole wave when any lane needs it (no accuracy cliff).
        v2f spr;
        if (__any(__builtin_fminf(d2p.x, d2p.y) < D2P_MIN)) {
          v2f sq_p = {fsqrt(d2p.x), fsqrt(d2p.y)};
          v2f pa = sq_p*cprx;
          spr = (v2f){fexp2(pa.x), fexp2(pa.y)};                           // exact
        } else {
          spr = zerov;                                                     // exp(-50d)~0
        }
        const v2f fsl = fs*l2e;
        const v2f nfsl = zerov - fsl;
        const v2f E2 = {fexp2(nfsl.x), fexp2(nfsl.y)};  // exp(-fs), shared x3
        PKGATE(sf,  gcF, spa2[0][rp], sma2[0][rp], cp0, cp1);
        PKGATE(scl, gcC, spa2[1][rp], sma2[1][rp], cp2, cp3);
        PKGATE(spr, gcP, spa2[2][rp], sma2[2][rp], cp4, cp5);
      }

      if (docol) {   // column partials: horizontal add, then reduce 4 g-groups
        float h0 = cp0.x+cp0.y, h1 = cp1.x+cp1.y, h2 = cp2.x+cp2.y;
        float h3 = cp3.x+cp3.y, h4 = cp4.x+cp4.y, h5 = cp5.x+cp5.y;
        h0 += __shfl_xor(h0,16); h0 += __shfl_xor(h0,32);
        h1 += __shfl_xor(h1,16); h1 += __shfl_xor(h1,32);
        h2 += __shfl_xor(h2,16); h2 += __shfl_xor(h2,32);
        h3 += __shfl_xor(h3,16); h3 += __shfl_xor(h3,32);
        h4 += __shfl_xor(h4,16); h4 += __shfl_xor(h4,32);
        h5 += __shfl_xor(h5,16); h5 += __shfl_xor(h5,32);
        if (lane < 16) {
          float* ca = colacc[p][w][jloc];
          ca[0]=h0; ca[1]=h1; ca[2]=h2; ca[3]=h3; ca[4]=h4; ca[5]=h5;
        }
      }
    }

    // (D) stage WRITES for next tile into the other buffer
    if (more) {
      const int nb = p^1;
      *(float4*)((char*)fnj[nb] + srow*128 + ((sseg*16)^ssw)) = f0;
      *(float4*)((char*)fnj[nb] + (srow+32)*128 + ((sseg*16)^ssw)) = f1;
      if (tid < 192) *(float4*)(scj[nb] + scrow*12 + scseg*4) = sv;
    }

    __syncthreads();   // one barrier per tile
    cprev=c; tjprev=tj;
  }

  // final flush (buffer parity of the last tile: p = (npt-1)&1)
  if (cprev>=1 && cprev<=31) {
    const int pl = (npt-1)&1;
    for (int s=tid; s<384; s+=256) {
      int jl=s/6, kk=s-6*jl;
      float v = colacc[pl][0][jl][kk]+colacc[pl][1][jl][kk]
              + colacc[pl][2][jl][kk]+colacc[pl][3][jl][kk];
      part2[(((size_t)b*31 + (cprev-1))*N_ + tjprev*64 + jl)*6 + kk] = v;
    }
  }

  // rows: unpack row-pairs, reduce the 16 j-columns across the 16-lane group
  float spa[3][4], sma[3][4];
  #pragma unroll
  for (int l=0;l<3;++l)
    #pragma unroll
    for (int rp=0;rp<2;++rp) {
      spa[l][2*rp]=spa2[l][rp].x; spa[l][2*rp+1]=spa2[l][rp].y;
      sma[l][2*rp]=sma2[l][rp].x; sma[l][2*rp+1]=sma2[l][rp].y;
    }
  #pragma unroll
  for (int l=0;l<3;++l)
    #pragma unroll
    for (int r=0;r<4;++r) {
      float a=spa[l][r], cc=sma[l][r];
      #pragma unroll
      for (int d=1; d<16; d<<=1){ a += __shfl_xor(a,d); cc += __shfl_xor(cc,d); }
      spa[l][r]=a; sma[l][r]=cc;
    }
  if (col==0) {
    #pragma unroll
    for (int r=0;r<4;++r) {
      float* o = part_row + (((size_t)b*NCH + k)*N_ + irow0 + g*4 + r)*6;
      o[0]=spa[0][r]; o[1]=sma[0][r];
      o[2]=spa[1][r]; o[3]=sma[1][r];
      o[4]=spa[2][r]; o[5]=sma[2][r];
    }
  }
}

// ---------------- finalize: combine row+col partials, log1p + mean ----------------
extern "C" __global__ __launch_bounds__(256) void fin1_k(
    const float* __restrict__ part_row, const float* __restrict__ part2,
    float* __restrict__ partial)
{
  const int pt = blockIdx.x*256 + threadIdx.x;   // b*N_ + i
  const int b = pt >> 12;
  const int i = pt & (N_-1);
  float s[6] = {0.f,0.f,0.f,0.f,0.f,0.f};
  #pragma unroll
  for (int kc=0;kc<NCH;++kc) {
    const float* pp = part_row + (((size_t)b*NCH + kc)*N_ + i)*6;
    #pragma unroll
    for (int q=0;q<6;++q) s[q] += pp[q];
  }
  for (int c=1;c<=31;++c) {
    const float* pp = part2 + (((size_t)b*31 + (c-1))*N_ + i)*6;
    #pragma unroll
    for (int q=0;q<6;++q) s[q] += pp[q];
  }
  float acc = log1pf(s[0]) + log1pf(s[1]) + log1pf(s[2])
            + log1pf(s[3]) + log1pf(s[4]) + log1pf(s[5]);
  #pragma unroll
  for (int d=32; d; d>>=1) acc += __shfl_xor(acc, d);
  __shared__ float wsum[4];
  if ((threadIdx.x&63)==0) wsum[threadIdx.x>>6] = acc;
  __syncthreads();
  if (threadIdx.x==0) partial[blockIdx.x] = wsum[0]+wsum[1]+wsum[2]+wsum[3];
}

extern "C" __global__ void fin2_k(const float* __restrict__ partial, float* __restrict__ out)
{
  float acc = partial[threadIdx.x];   // 64 threads
  #pragma unroll
  for (int d=32; d; d>>=1) acc += __shfl_xor(acc, d);
  if (threadIdx.x==0) out[0] = -acc * (1.0f/(float)BN_);
}

extern "C" void kernel_launch(void* const* d_in, const int* in_sizes, int n_in,
                              void* d_out, int out_size, void* d_ws, size_t ws_size,
                              hipStream_t stream)
{
  const float* flow  = (const float*)d_in[0];
  const float* color = (const float*)d_in[1];
  const float* coord = (const float*)d_in[2];
  const float* feat  = (const float*)d_in[3];
  char* ws = (char*)d_ws;
  unsigned short* fn = (unsigned short*)ws;                       // 2 MB
  float* scal     = (float*)(ws + 2097152);                       // 768 KB
  float* part_row = (float*)(ws + 2883584);                       // 786 KB [b][2][N][6]
  float* part2    = (float*)(ws + 3670016);                       // 12.2 MB [b][31][N][6]
  float* partial  = (float*)(ws + 15859712);                      // 256 B
  float* outp = (float*)d_out;
  hipLaunchKernelGGL(prep_k, dim3(BN_/4), dim3(256), 0, stream,
                     flow, color, coord, feat, fn, scal);
  hipLaunchKernelGGL(main_k, dim3(NT*NCH, B_), dim3(256), 0, stream,
                     fn, scal, part_row, part2);
  hipLaunchKernelGGL(fin1_k, dim3(BN_/256), dim3(256), 0, stream,
                     part_row, part2, partial);
  hipLaunchKernelGGL(fin2_k, dim3(1), dim3(64), 0, stream, partial, outp);
}

// Round 19
// 94.856 us; speedup vs baseline: 1.0100x; 1.0100x over previous
//
#include <hip/hip_runtime.h>
#include <math.h>

#define B_ 4
#define N_ 4096
#define BN_ (B_*N_)
#define NT 64                 /* 64 tiles of 64 rows */
#define NCH 2                 /* k=0: c in [0,16), k=1: c in [16,33) */

typedef __bf16 v8bf __attribute__((ext_vector_type(8)));
typedef unsigned short u16x8 __attribute__((ext_vector_type(8)));
typedef float v4f __attribute__((ext_vector_type(4)));
typedef float v2f __attribute__((ext_vector_type(2)));

#define LOG2E 1.44269504088896340736f
#define CPROX (-50.0f*LOG2E)            /* -1/(2*sigma^2) * log2(e) */
#define INVSQRT3 0.57735026918962576f
/* smoothstep sigmoid approx: sigmoid(5(s-tau)) ~ S((s-tau)/1.4 + 0.5) */
#define GS (1.0f/1.4f)
#define GC_FLOW  (0.5f - 0.8f*GS)
#define GC_COLOR (0.5f - 0.7f*GS)
#define GC_PROX  (0.5f - 0.5f*GS)
/* prox fast path: d2p > 0.09 (d > 0.3) -> spr = exp(-50d) <= 3e-7 ~ 0 */
#define D2P_MIN 0.09f

__device__ __forceinline__ float fexp2(float x){ return __builtin_amdgcn_exp2f(x); }
__device__ __forceinline__ float fsqrt(float x){ return __builtin_amdgcn_sqrtf(x); }

// packed smoothstep gate on a float2 of (r, r+1) pairs
#define PKGATE(s2_, gcv_, SPA, SMA, CPA, CPB)                          \
  { v2f t_ = s2_*GSv + gcv_;                                           \
    t_ = __builtin_elementwise_max(t_, zerov);                         \
    t_ = __builtin_elementwise_min(t_, onev);                          \
    v2f t2_ = t_*t_;                                                   \
    v2f u_  = t_*m2v + c3v;                                            \
    v2f a_  = (t2_*u_)*fsl;                                            \
    v2f e1_ = {fexp2(a_.x), fexp2(a_.y)};                              \
    v2f e2_ = E2*e1_;                                                  \
    SPA += e1_; SMA += e2_; CPA += e1_; CPB += e2_; }

// flush column partials of a finished phase (parity par_), tiles base_..base_+cnt_-1
#define FLUSHP(par_, base_, cnt_)                                                 \
  for (int s_=0; s_<(cnt_); ++s_) {                                               \
    const int cf_ = (base_) + s_;                                                 \
    if (cf_>=1 && cf_<=31) {                                                      \
      const int tjf_ = (ti + cf_) & 63;                                           \
      for (int x_=tid; x_<384; x_+=256) {                                         \
        int jl_=x_/6, kk_=x_-6*jl_;                                               \
        float v_ = colacc[par_][s_][0][jl_][kk_]+colacc[par_][s_][1][jl_][kk_]    \
                 + colacc[par_][s_][2][jl_][kk_]+colacc[par_][s_][3][jl_][kk_];   \
        part2[(((size_t)b*31 + (cf_-1))*N_ + tjf_*64 + jl_)*6 + kk_] = v_;        \
      }                                                                           \
    }                                                                             \
  }

// ---------------- prep: normalize features -> bf16, per-point scalars ----------------
extern "C" __global__ __launch_bounds__(256) void prep_k(
    const float* __restrict__ flow, const float* __restrict__ color,
    const float* __restrict__ coord, const float* __restrict__ feat,
    unsigned short* __restrict__ fn, float* __restrict__ scal)
{
  const int wave = blockIdx.x*4 + (threadIdx.x>>6);
  const int lane = threadIdx.x & 63;
  float v = feat[(size_t)wave*64 + lane];
  float ss = v*v;
  #pragma unroll
  for (int d=32; d; d>>=1) ss += __shfl_xor(ss, d);
  float sc = 1.0f/(sqrtf(ss)+1e-7f);     // matches ref: f/(||f||+1e-7)
  float x = v*sc;
  unsigned u = __builtin_bit_cast(unsigned, x);
  unsigned r = (u + 0x7fffu + ((u>>16)&1u)) >> 16;   // RN-even f32->bf16
  fn[(size_t)wave*64+lane] = (unsigned short)r;
  if (lane==0) {
    float fx=flow[wave*3+0], fy=flow[wave*3+1], fz=flow[wave*3+2];
    float rn = 1.0f/sqrtf(fx*fx+fy*fy+fz*fz + 1e-8f);
    const float k = 1.0f/255.0f;
    float cx=color[wave*3+0]*k, cy=color[wave*3+1]*k, cz=color[wave*3+2]*k;
    float px=coord[wave*3+0], py=coord[wave*3+1], pz=coord[wave*3+2];
    float* o = scal + (size_t)wave*12;
    o[0]=fx*rn; o[1]=fy*rn; o[2]=fz*rn;
    o[3]=cx; o[4]=cy; o[5]=cz;
    o[6]=cx*cx+cy*cy+cz*cz;
    o[7]=px; o[8]=py; o[9]=pz;
    o[10]=px*px+py*py+pz*pz;
    o[11]=0.f;
  }
}

// ---------- main: symmetric ring, 2 j-tiles per barrier-phase (R19) ----------
// block (b, ti, k): j-tiles tj=(ti+c)&63; k=0: c=0..15, k=1: c=16..32.
// Phases of 2 tiles (k=1 phase 0 has 1): barrier count 17 -> 9 per block.
// c=0 (diag) and c=32 (antipode, computed from both ends) are rows-only.
// (256,2): compiler VGPR budget = 256/min_waves (R5/R11/R16); live ~112 needs 128.
extern "C" __global__ __launch_bounds__(256,2) void main_k(
    const unsigned short* __restrict__ fn, const float* __restrict__ scal,
    float* __restrict__ part_row, float* __restrict__ part2)
{
  __shared__ unsigned short fnj[2][2][64*64];   // 32 KB: [phase][slot], swizzled rows
  __shared__ float scj[2][2][64*12];            // 12 KB
  __shared__ float colacc[2][2][4][64][6];      // 24 KB per-wave column partials

  const int ti = blockIdx.x & 63;
  const int k  = blockIdx.x >> 6;            // 0..1
  const int b  = blockIdx.y;
  const int c0 = k*16;
  const int npt = 16 + k;                    // 16 or 17 tiles
  const int nphase = (npt + 1) >> 1;         // 8 or 9
  const int ph0cnt = (npt & 1) ? 1 : 2;

  const int tid  = threadIdx.x;
  const int w    = tid >> 6;
  const int lane = tid & 63;
  const int g    = lane >> 4;
  const int col  = lane & 15;
  const int irow0 = ti*64 + w*16;

  const unsigned short* fnb = fn + (size_t)b*N_*64;
  const float* scb = scal + (size_t)b*N_*12;

  // staging geometry (each thread: 2 fn-rows-of-16B + 1 scj-16B if tid<192)
  const int srow = tid>>3, sseg = tid&7;
  const int ssw  = (srow&7)<<4;              // (srow+32)&7 == srow&7
  const int scrow = tid/3, scseg = tid-3*(tid/3);

  // A fragments: row = lane&15, kk = (lane>>4)*8 + e (two K=32 halves), held in regs
  const int arow = irow0 + col;
  v8bf a0 = __builtin_bit_cast(v8bf, *(const u16x8*)(fnb + (size_t)arow*64 + g*8));
  v8bf a1 = __builtin_bit_cast(v8bf, *(const u16x8*)(fnb + (size_t)arow*64 + 32 + g*8));

  // i-side scalars packed as float2 over row-pairs (r, r+1), rp in {0,1}
  v2f fhi[2][3], ci2[2][3], pi2[2][3];
  #pragma unroll
  for (int rp=0;rp<2;++rp) {
    const float* sA = scb + (size_t)(irow0 + g*4 + 2*rp)*12;
    const float* sB = sA + 12;
    v4f a0s = *(const v4f*)(sA), a1s = *(const v4f*)(sA+4), a2s = *(const v4f*)(sA+8);
    v4f b0s = *(const v4f*)(sB), b1s = *(const v4f*)(sB+4), b2s = *(const v4f*)(sB+8);
    fhi[rp][0] = (v2f){a0s.x, b0s.x}; fhi[rp][1] = (v2f){a0s.y, b0s.y}; fhi[rp][2] = (v2f){a0s.z, b0s.z};
    ci2[rp][0] = (v2f){a0s.w, b0s.w}; ci2[rp][1] = (v2f){a1s.x, b1s.x}; ci2[rp][2] = (v2f){a1s.y, b1s.y};
    pi2[rp][0] = (v2f){a1s.w, b1s.w}; pi2[rp][1] = (v2f){a2s.x, b2s.x}; pi2[rp][2] = (v2f){a2s.y, b2s.y};
  }

  const v2f zerov = {0.f,0.f}, onev = {1.f,1.f};
  const v2f GSv = {GS,GS}, m2v = {-2.f,-2.f}, c3v = {3.f,3.f};
  const v2f gcF = {GC_FLOW,GC_FLOW}, gcC = {GC_COLOR,GC_COLOR}, gcP = {GC_PROX,GC_PROX};
  const v2f l2e = {LOG2E,LOG2E}, cprx = {CPROX,CPROX}, nis3 = {-INVSQRT3,-INVSQRT3};

  // row accumulators, packed over row-pairs
  v2f spa2[3][2], sma2[3][2];
  #pragma unroll
  for (int l=0;l<3;++l)
    #pragma unroll
    for (int rp=0;rp<2;++rp){ spa2[l][rp]=zerov; sma2[l][rp]=zerov; }

  // prologue: stage phase-0 tiles into buffers [0][s]
  for (int s=0; s<ph0cnt; ++s) {
    const int tj = (ti + c0 + s) & 63;
    const unsigned short* fng = fnb + (size_t)tj*4096;
    const float* scg = scb + (size_t)tj*768;
    float4 f0 = *(const float4*)(fng + (size_t)srow*64 + sseg*8);
    float4 f1 = *(const float4*)(fng + (size_t)(srow+32)*64 + sseg*8);
    *(float4*)((char*)fnj[0][s] + srow*128 + ((sseg*16)^ssw)) = f0;
    *(float4*)((char*)fnj[0][s] + (srow+32)*128 + ((sseg*16)^ssw)) = f1;
    if (tid < 192)
      *(float4*)(scj[0][s] + scrow*12 + scseg*4) = *(const float4*)(scg + (size_t)scrow*12 + scseg*4);
  }
  __syncthreads();

  int cbase = c0, cnt = ph0cnt;
  int pbase = 0, pcnt = 0;
  for (int ph = 0; ph < nphase; ++ph) {
    const int p  = ph & 1;
    const int pn = p ^ 1;
    const int cnt_next = (ph+1 < nphase) ? 2 : 0;
    const int cbase_next = cbase + cnt;

    // flush previous phase's columns (parity pn), overlaps this phase's compute
    if (pcnt) { FLUSHP(pn, pbase, pcnt); }

    const int smax = cnt > cnt_next ? cnt : cnt_next;
    for (int s = 0; s < smax; ++s) {
      // (A) issue loads for next phase's slot s (hidden under this slot's compute)
      float4 f0, f1, sv;
      const bool doload = s < cnt_next;
      if (doload) {
        const int tjn = (ti + cbase_next + s) & 63;
        const unsigned short* fng = fnb + (size_t)tjn*4096;
        const float* scg = scb + (size_t)tjn*768;
        f0 = *(const float4*)(fng + (size_t)srow*64 + sseg*8);
        f1 = *(const float4*)(fng + (size_t)(srow+32)*64 + sseg*8);
        if (tid < 192) sv = *(const float4*)(scg + (size_t)scrow*12 + scseg*4);
      }

      if (s < cnt) {
        const int c  = cbase + s;
        const bool docol = (c>=1 && c<=31);

        #pragma unroll
        for (int sub=0; sub<4; ++sub) {
          const int jloc = sub*16 + col;
          const int sw = (jloc&7)<<4;
          const char* rowp = (const char*)fnj[p][s] + jloc*128;
          v8bf b0 = __builtin_bit_cast(v8bf, *(const u16x8*)(rowp + ((g*16) ^ sw)));
          v8bf b1 = __builtin_bit_cast(v8bf, *(const u16x8*)(rowp + ((64 + g*16) ^ sw)));
          v4f j0 = *(const v4f*)(scj[p][s] + jloc*12);
          v4f j1 = *(const v4f*)(scj[p][s] + jloc*12 + 4);
          v4f j2 = *(const v4f*)(scj[p][s] + jloc*12 + 8);

          v4f acc = {0.f,0.f,0.f,0.f};
          acc = __builtin_amdgcn_mfma_f32_16x16x32_bf16(a0, b0, acc, 0,0,0);
          acc = __builtin_amdgcn_mfma_f32_16x16x32_bf16(a1, b1, acc, 0,0,0);

          const v2f jf0={j0.x,j0.x}, jf1={j0.y,j0.y}, jf2={j0.z,j0.z};
          const v2f jc0={j0.w,j0.w}, jc1={j1.x,j1.x}, jc2={j1.y,j1.y};
          const v2f jp0={j1.w,j1.w}, jp1={j2.x,j2.x}, jp2={j2.y,j2.y};

          v2f cp0=zerov, cp1=zerov, cp2=zerov, cp3=zerov, cp4=zerov, cp5=zerov;

          #pragma unroll
          for (int rp=0;rp<2;++rp) {
            const v2f fs = {acc[2*rp], acc[2*rp+1]};
            const v2f sf = fhi[rp][0]*jf0 + fhi[rp][1]*jf1 + fhi[rp][2]*jf2;
            v2f dc0 = ci2[rp][0]-jc0, dc1 = ci2[rp][1]-jc1, dc2 = ci2[rp][2]-jc2;
            v2f d2c = dc0*dc0 + dc1*dc1 + dc2*dc2;
            v2f sq_c = {fsqrt(d2c.x), fsqrt(d2c.y)};
            const v2f scl = sq_c*nis3 + onev;
            v2f dp0 = pi2[rp][0]-jp0, dp1 = pi2[rp][1]-jp1, dp2 = pi2[rp][2]-jp2;
            v2f d2p = dp0*dp0 + dp1*dp1 + dp2*dp2;
            v2f spr;
            if (__any(__builtin_fminf(d2p.x, d2p.y) < D2P_MIN)) {
              v2f sq_p = {fsqrt(d2p.x), fsqrt(d2p.y)};
              v2f pa = sq_p*cprx;
              spr = (v2f){fexp2(pa.x), fexp2(pa.y)};
            } else {
              spr = zerov;
            }
            const v2f fsl = fs*l2e;
            const v2f nfsl = zerov - fsl;
            const v2f E2 = {fexp2(nfsl.x), fexp2(nfsl.y)};
            PKGATE(sf,  gcF, spa2[0][rp], sma2[0][rp], cp0, cp1);
            PKGATE(scl, gcC, spa2[1][rp], sma2[1][rp], cp2, cp3);
            PKGATE(spr, gcP, spa2[2][rp], sma2[2][rp], cp4, cp5);
          }

          if (docol) {
            float h0 = cp0.x+cp0.y, h1 = cp1.x+cp1.y, h2 = cp2.x+cp2.y;
            float h3 = cp3.x+cp3.y, h4 = cp4.x+cp4.y, h5 = cp5.x+cp5.y;
            h0 += __shfl_xor(h0,16); h0 += __shfl_xor(h0,32);
            h1 += __shfl_xor(h1,16); h1 += __shfl_xor(h1,32);
            h2 += __shfl_xor(h2,16); h2 += __shfl_xor(h2,32);
            h3 += __shfl_xor(h3,16); h3 += __shfl_xor(h3,32);
            h4 += __shfl_xor(h4,16); h4 += __shfl_xor(h4,32);
            h5 += __shfl_xor(h5,16); h5 += __shfl_xor(h5,32);
            if (lane < 16) {
              float* ca = colacc[p][s][w][jloc];
              ca[0]=h0; ca[1]=h1; ca[2]=h2; ca[3]=h3; ca[4]=h4; ca[5]=h5;
            }
          }
        }
      }

      // (D) write staged regs into next phase's buffers (reads of [pn] done last phase)
      if (doload) {
        *(float4*)((char*)fnj[pn][s] + srow*128 + ((sseg*16)^ssw)) = f0;
        *(float4*)((char*)fnj[pn][s] + (srow+32)*128 + ((sseg*16)^ssw)) = f1;
        if (tid < 192) *(float4*)(scj[pn][s] + scrow*12 + scseg*4) = sv;
      }
    }

    __syncthreads();   // one barrier per 2-tile phase
    pbase = cbase; pcnt = cnt;
    cbase = cbase_next; cnt = cnt_next;
  }

  // final flush (parity of last phase)
  { const int pl = (nphase-1)&1; FLUSHP(pl, pbase, pcnt); }

  // rows: unpack row-pairs, reduce the 16 j-columns across the 16-lane group
  float spa[3][4], sma[3][4];
  #pragma unroll
  for (int l=0;l<3;++l)
    #pragma unroll
    for (int rp=0;rp<2;++rp) {
      spa[l][2*rp]=spa2[l][rp].x; spa[l][2*rp+1]=spa2[l][rp].y;
      sma[l][2*rp]=sma2[l][rp].x; sma[l][2*rp+1]=sma2[l][rp].y;
    }
  #pragma unroll
  for (int l=0;l<3;++l)
    #pragma unroll
    for (int r=0;r<4;++r) {
      float a=spa[l][r], cc=sma[l][r];
      #pragma unroll
      for (int d=1; d<16; d<<=1){ a += __shfl_xor(a,d); cc += __shfl_xor(cc,d); }
      spa[l][r]=a; sma[l][r]=cc;
    }
  if (col==0) {
    #pragma unroll
    for (int r=0;r<4;++r) {
      float* o = part_row + (((size_t)b*NCH + k)*N_ + irow0 + g*4 + r)*6;
      o[0]=spa[0][r]; o[1]=sma[0][r];
      o[2]=spa[1][r]; o[3]=sma[1][r];
      o[4]=spa[2][r]; o[5]=sma[2][r];
    }
  }
}

// ---------------- finalize: combine row+col partials, log1p + mean ----------------
extern "C" __global__ __launch_bounds__(64) void fin1_k(
    const float* __restrict__ part_row, const float* __restrict__ part2,
    float* __restrict__ partial)
{
  const int pt = blockIdx.x*64 + threadIdx.x;   // b*N_ + i
  const int b = pt >> 12;
  const int i = pt & (N_-1);
  float s[6] = {0.f,0.f,0.f,0.f,0.f,0.f};
  #pragma unroll
  for (int kc=0;kc<NCH;++kc) {
    const float* pp = part_row + (((size_t)b*NCH + kc)*N_ + i)*6;
    #pragma unroll
    for (int q=0;q<6;++q) s[q] += pp[q];
  }
  for (int c=1;c<=31;++c) {
    const float* pp = part2 + (((size_t)b*31 + (c-1))*N_ + i)*6;
    #pragma unroll
    for (int q=0;q<6;++q) s[q] += pp[q];
  }
  float acc = log1pf(s[0]) + log1pf(s[1]) + log1pf(s[2])
            + log1pf(s[3]) + log1pf(s[4]) + log1pf(s[5]);
  #pragma unroll
  for (int d=32; d; d>>=1) acc += __shfl_xor(acc, d);
  if (threadIdx.x==0) partial[blockIdx.x] = acc;
}

extern "C" __global__ void fin2_k(const float* __restrict__ partial, float* __restrict__ out)
{
  const int tid = threadIdx.x;   // 256 threads
  float acc = partial[tid];
  #pragma unroll
  for (int d=32; d; d>>=1) acc += __shfl_xor(acc, d);
  __shared__ float wsum[4];
  if ((tid&63)==0) wsum[tid>>6] = acc;
  __syncthreads();
  if (tid==0) out[0] = -(wsum[0]+wsum[1]+wsum[2]+wsum[3]) * (1.0f/(float)BN_);
}

extern "C" void kernel_launch(void* const* d_in, const int* in_sizes, int n_in,
                              void* d_out, int out_size, void* d_ws, size_t ws_size,
                              hipStream_t stream)
{
  const float* flow  = (const float*)d_in[0];
  const float* color = (const float*)d_in[1];
  const float* coord = (const float*)d_in[2];
  const float* feat  = (const float*)d_in[3];
  char* ws = (char*)d_ws;
  unsigned short* fn = (unsigned short*)ws;                       // 2 MB
  float* scal     = (float*)(ws + 2097152);                       // 768 KB
  float* part_row = (float*)(ws + 2883584);                       // 786 KB [b][2][N][6]
  float* part2    = (float*)(ws + 3670016);                       // 12.2 MB [b][31][N][6]
  float* partial  = (float*)(ws + 15859712);                      // 1 KB (256 floats)
  float* outp = (float*)d_out;
  hipLaunchKernelGGL(prep_k, dim3(BN_/4), dim3(256), 0, stream,
                     flow, color, coord, feat, fn, scal);
  hipLaunchKernelGGL(main_k, dim3(NT*NCH, B_), dim3(256), 0, stream,
                     fn, scal, part_row, part2);
  hipLaunchKernelGGL(fin1_k, dim3(BN_/64), dim3(64), 0, stream,
                     part_row, part2, partial);
  hipLaunchKernelGGL(fin2_k, dim3(1), dim3(256), 0, stream, partial, outp);
}